// Round 4
// baseline (226.710 us; speedup 1.0000x reference)
//
#include <hip/hip_runtime.h>

// G=14, B=64, T=2048, H=6
#define Gc 14
#define Hc 6
#define NPc (64*2048)          // B*T points
#define LOG_2PI 1.8378770664093453f

__device__ __forceinline__ float frcp(float x){ return __builtin_amdgcn_rcpf(x); }
__device__ __forceinline__ float frsq(float x){ return __builtin_amdgcn_rsqf(x); }

// DPP lane exchange within quads (1-cycle VALU, no LDS):
//   0xA0 = quad_perm [0,0,2,2]  (each lane-pair gets its EVEN lane's value)
//   0xF5 = quad_perm [1,1,3,3]  (each lane-pair gets its ODD lane's value)
//   0xB1 = quad_perm [1,0,3,2]  (swap within pair)
template<int CTRL>
__device__ __forceinline__ float dppf(float x){
    union { float f; int i; } u; u.f = x;
    u.i = __builtin_amdgcn_update_dpp(0, u.i, CTRL, 0xF, 0xF, true);
    return u.f;
}
template<int OQ>
__device__ __forceinline__ float bcast(float x){
    return (OQ == 0) ? dppf<0xA0>(x) : dppf<0xF5>(x);
}

// Global channel k -> (owner lane parity, local index).
// Lane q owns global channels {2q, 2q+1, 4+q} as locals {0,1,2}.
constexpr int oq_of(int k){ return (k < 4) ? (k >> 1) : (k - 4); }
constexpr int lj_of(int k){ return (k < 4) ? (k & 1) : 2; }

struct Coef { float a1, a2, s1, s2; };

// Shared scalar head (computed redundantly on both lanes of a pair).
// Identities: x3 = x1*(r1*irs) - x2*(r2*irs); x4 = sgn(C1C2)*irs*(x1*r2 + x2*r1);
// logC == 0 exactly (std3*std4*|C1C2| == 1).
__device__ __forceinline__ Coef head(float C1, float C2){
    const float r1 = (C1 == 0.0f) ? 0.0f : frcp(C1);
    const float r2 = (C2 == 0.0f) ? 0.0f : frcp(C2);
    const float var3 = fmaf(r1, r1, r2 * r2);
    const float irs  = frsq(var3);                  // 1/std3
    const float si   = copysignf(irs, C1 * C2);
    Coef c; c.a1 = r1 * irs; c.a2 = r2 * irs; c.s1 = r1 * si; c.s2 = r2 * si;
    return c;
}
// Per-channel pair update: 2 mul + 2 fma.
__device__ __forceinline__ void upd(float &x, float &y, const Coef &c){
    const float t = y * c.a2, u = y * c.s1;
    const float nx = fmaf(x, c.a1, -t);
    y = fmaf(x, c.s2, u);
    x = nx;
}

template<int K>
__device__ __forceinline__ void sweep1(float (&cur)[Gc][3], float (&nxt)[Gc][3],
                                       float (&bb)[Gc], float &LC, int q){
    constexpr int OQ = oq_of(K), LJ = lj_of(K);
    constexpr int n = Gc - K;
#pragma unroll
    for (int i = 0; i < n - 1; ++i){
        const float C1 = bcast<OQ>(cur[i][LJ]);
        const float C2 = bcast<OQ>(cur[i + 1][LJ]);
        const Coef c = head(C1, C2);
        upd(cur[i][0], cur[i + 1][0], c);
        upd(cur[i][1], cur[i + 1][1], c);
        upd(cur[i][2], cur[i + 1][2], c);
        upd(nxt[i][0], nxt[i + 1][0], c);
        upd(nxt[i][1], nxt[i + 1][1], c);
        upd(nxt[i][2], nxt[i + 1][2], c);
        upd(bb[i], bb[i + 1], c);
    }
    // LC -= log|cur[n-1][K]| ; the value lives on the owner lane only.
    const float t = __logf(fabsf(cur[n - 1][LJ]));
    LC -= (q == OQ) ? t : 0.0f;
}

template<int K>
__device__ __forceinline__ void sweep2(float (&nxt)[Gc][3], float (&bb)[Gc],
                                       float* __restrict__ outN,
                                       float* __restrict__ outB,
                                       int p, int q){
    constexpr int OQ = oq_of(K), LJ = lj_of(K);
    constexpr int n = (Gc - Hc) - K;   // 8 - K
#pragma unroll
    for (int i = 0; i < n - 1; ++i){
        const float C1 = bcast<OQ>(nxt[i][LJ]);
        const float C2 = bcast<OQ>(nxt[i + 1][LJ]);
        const Coef c = head(C1, C2);
        // cur is write-only (dead) in phase 2 -> skipped entirely.
        upd(nxt[i][0], nxt[i + 1][0], c);
        upd(nxt[i][1], nxt[i + 1][1], c);
        upd(nxt[i][2], nxt[i + 1][2], c);
        upd(bb[i], bb[i + 1], c);
    }
    constexpr int m = n - 1;           // popped slot -> kept_n[K], kept_b[K]
    char* ob = (char*)outN + (size_t)K * (NPc * 24) + (size_t)p * 24;
    *(float2*)(ob + 8 * q) = make_float2(nxt[m][0], nxt[m][1]);
    *(float*)(ob + 16 + 4 * q) = nxt[m][2];
    if (q == 0) outB[(size_t)K * NPc + p] = bb[m];
}

__global__ void __launch_bounds__(512, 4)
gaussmerge_kernel(const float* __restrict__ cur_in,
                  const float* __restrict__ nxt_in,
                  const float* __restrict__ b_in,
                  float* __restrict__ out)
{
    const int tid = threadIdx.x;
    const int q = tid & 1;                         // role within lane pair
    const int p = blockIdx.x * 256 + (tid >> 1);   // point index

    float cur[Gc][3], nxt[Gc][3], bb[Gc];

    const char* cbase = (const char*)cur_in + (size_t)p * 24;
    const char* nbase = (const char*)nxt_in + (size_t)p * 24;
#pragma unroll
    for (int g = 0; g < Gc; ++g){
        const char* cb = cbase + (size_t)g * (NPc * 24);
        const char* nb = nbase + (size_t)g * (NPc * 24);
        const float2 cv = *(const float2*)(cb + 8 * q);
        const float  cs = *(const float* )(cb + 16 + 4 * q);
        const float2 nv = *(const float2*)(nb + 8 * q);
        const float  ns = *(const float* )(nb + 16 + 4 * q);
        cur[g][0] = cv.x; cur[g][1] = cv.y; cur[g][2] = cs;
        nxt[g][0] = nv.x; nxt[g][1] = nv.y; nxt[g][2] = ns;
        bb[g] = b_in[(size_t)g * NPc + p];
    }

    float LC = 0.0f;

    // ---- phase 1 ----
    sweep1<0>(cur, nxt, bb, LC, q);
    sweep1<1>(cur, nxt, bb, LC, q);
    sweep1<2>(cur, nxt, bb, LC, q);
    sweep1<3>(cur, nxt, bb, LC, q);
    sweep1<4>(cur, nxt, bb, LC, q);
    sweep1<5>(cur, nxt, bb, LC, q);

    // ---- phase 2 + outputs ----
    float* outN = out;                              // (6, B, T, H)
    float* outB = out + (size_t)Hc * NPc * Hc;      // (6, B, T)
    float* outL = outB + (size_t)Hc * NPc;          // (B, T)

    sweep2<0>(nxt, bb, outN, outB, p, q);
    sweep2<1>(nxt, bb, outN, outB, p, q);
    sweep2<2>(nxt, bb, outN, outB, p, q);
    sweep2<3>(nxt, bb, outN, outB, p, q);
    sweep2<4>(nxt, bb, outN, outB, p, q);
    sweep2<5>(nxt, bb, outN, outB, p, q);

    // ---- LC: combine lane-pair partials, add bias-norm terms once ----
    float lcs = LC + dppf<0xB1>(LC);                // pair sum (both lanes)
    lcs += -0.5f * (LOG_2PI + bb[0] * bb[0]);
    lcs += -0.5f * (LOG_2PI + bb[1] * bb[1]);
    if (q == 0) outL[p] = lcs;
}

extern "C" void kernel_launch(void* const* d_in, const int* in_sizes, int n_in,
                              void* d_out, int out_size, void* d_ws, size_t ws_size,
                              hipStream_t stream) {
    const float* cur = (const float*)d_in[0];
    const float* nxt = (const float*)d_in[1];
    const float* bia = (const float*)d_in[2];
    float* out = (float*)d_out;

    // 2 threads per point: 512-thread blocks cover 256 points each.
    dim3 grid((NPc * 2) / 512), block(512);
    gaussmerge_kernel<<<grid, block, 0, stream>>>(cur, nxt, bia, out);
}

// Round 5
// 40.631 us; speedup vs baseline: 5.5797x; 5.5797x over previous
//
#include <hip/hip_runtime.h>

// G=14, B=64, T=2048, H=6
#define Gc 14
#define Hc 6
#define NPc (64*2048)          // B*T points
#define LOG_2PI 1.8378770664093453f

__device__ __forceinline__ float frsq(float x){ return __builtin_amdgcn_rsqf(x); }

// DPP quad_perm broadcast of lane L's value to all 4 lanes of the quad.
template<int CTRL>
__device__ __forceinline__ float dppf(float x){
    union { float f; int i; } u; u.f = x;
    u.i = __builtin_amdgcn_update_dpp(0, u.i, CTRL, 0xF, 0xF, true);
    return u.f;
}
template<int L>
__device__ __forceinline__ float bcast(float x){ return dppf<L * 0x55>(x); }

// Head coefficients. With S = rsqrt(C1^2+C2^2):
//   x3 = a1*x1 - a2*x2,  x4 = s2*x1 + s1*x2
//   s1 = C2*S, s2 = C1*S, a1 = copysign(s1,C1) = sgn(C1)|C2|S, a2 = copysign(s2,C2)
// Head channel check: x4(C1,C2) = C1^2 S + C2^2 S = sqrt(C1^2+C2^2) = 1/std4. ✓
// logC == 0 exactly (std3*std4*|C1 C2| == 1) -> dropped.
struct Coef { float a1, a2, s1, s2; };
__device__ __forceinline__ Coef head(float C1, float C2){
    const float S = frsq(fmaf(C1, C1, C2 * C2));   // 1 transcendental
    Coef c;
    c.s1 = C2 * S;
    c.s2 = C1 * S;
    c.a1 = copysignf(c.s1, C1);
    c.a2 = copysignf(c.s2, C2);
    return c;
}
// Uniform per-component pair update: 2 mul + 2 fma.
__device__ __forceinline__ void upd(float &x, float &y, const Coef &c){
    const float t = y * c.a2, u = y * c.s1;
    const float nx = fmaf(x, c.a1, -t);
    y = fmaf(x, c.s2, u);
    x = nx;
}

// One sweep of n-1 chained gprods; head value = channel at comp C of lane L.
template<int L, int C, int n>
__device__ __forceinline__ void do_sweep(float (&st)[Gc][4]){
#pragma unroll
    for (int i = 0; i < n - 1; ++i){
        const float C1 = bcast<L>(st[i][C]);
        const float C2 = bcast<L>(st[i + 1][C]);
        const Coef c = head(C1, C2);
        upd(st[i][0], st[i + 1][0], c);
        upd(st[i][1], st[i + 1][1], c);
        upd(st[i][2], st[i + 1][2], c);
        upd(st[i][3], st[i + 1][3], c);
    }
}

__global__ void __launch_bounds__(256, 4)
gaussmerge_kernel(const float* __restrict__ cur_in,
                  const float* __restrict__ nxt_in,
                  const float* __restrict__ b_in,
                  float* __restrict__ out)
{
    const int tid = threadIdx.x;
    const int q = tid & 3;                          // lane role in quad
    const int p = blockIdx.x * 64 + (tid >> 2);     // point index

    // Lane q owns: q0: cur0,cur1,nxt4 | q1: cur2,cur3,nxt5 | q2: cur4,cur5,b | q3: nxt0..3
    float st[Gc][4];

    const char* curp = (const char*)cur_in + (size_t)p * 24;
    const char* nxtp = (const char*)nxt_in + (size_t)p * 24;
    const char* aBase = (q == 3 ? nxtp : curp + 8 * q);
    const char* bBase = nxtp + (q == 3 ? 8 : 16);
    const float* bptr = b_in + p;

#pragma unroll
    for (int g = 0; g < Gc; ++g){
        const float2 A = *(const float2*)(aBase + (size_t)g * (NPc * 24));
        const float2 B = *(const float2*)(bBase + (size_t)g * (NPc * 24));
        const float bv = bptr[(size_t)g * NPc];
        st[g][0] = A.x; st[g][1] = A.y;
        const float c2v = (q == 1) ? B.y : B.x;     // nxt4 / nxt5 / (B.x for q3)
        st[g][2] = (q == 2) ? bv : c2v;
        st[g][3] = B.y;                              // live only on q3; finite junk elsewhere
    }

    float LC = 0.0f;

    // ---- phase 1: head = cur[k]; owner lane k/2, comp k&1; n = 14-k ----
    // After each sweep: LC -= log|cur[n-1][k]| (broadcast -> replicated on all lanes).
    do_sweep<0, 0, 14>(st); LC -= __logf(fabsf(bcast<0>(st[13][0])));
    do_sweep<0, 1, 13>(st); LC -= __logf(fabsf(bcast<0>(st[12][1])));
    do_sweep<1, 0, 12>(st); LC -= __logf(fabsf(bcast<1>(st[11][0])));
    do_sweep<1, 1, 11>(st); LC -= __logf(fabsf(bcast<1>(st[10][1])));
    do_sweep<2, 0, 10>(st); LC -= __logf(fabsf(bcast<2>(st[ 9][0])));
    do_sweep<2, 1,  9>(st); LC -= __logf(fabsf(bcast<2>(st[ 8][1])));

    // ---- phase 2: head = nxt[k]; owners k0-3 -> lane3 comp k, k4 -> lane0 comp2, k5 -> lane1 comp2 ----
    float* outN = out;                               // (6, B, T, H)
    float* outB = out + (size_t)Hc * NPc * Hc;       // (6, B, T)
    float* outL = outB + (size_t)Hc * NPc;           // (B, T)

#define PH2_STORE(K)                                                            \
    {                                                                           \
        constexpr int m = 7 - (K);  /* popped slot = kept_n[K], kept_b[K] */    \
        char* ob = (char*)outN + (size_t)(K) * (NPc * 24) + (size_t)p * 24;     \
        if (q == 3) {                                                           \
            *(float2*)(ob)     = make_float2(st[m][0], st[m][1]);               \
            *(float2*)(ob + 8) = make_float2(st[m][2], st[m][3]);               \
        } else if (q == 2) {                                                    \
            outB[(size_t)(K) * NPc + p] = st[m][2];                             \
        } else {                                                                \
            *(float*)(ob + 16 + 4 * q) = st[m][2];                              \
        }                                                                       \
    }

    do_sweep<3, 0, 8>(st); PH2_STORE(0)
    do_sweep<3, 1, 7>(st); PH2_STORE(1)
    do_sweep<3, 2, 6>(st); PH2_STORE(2)
    do_sweep<3, 3, 5>(st); PH2_STORE(3)
    do_sweep<0, 2, 4>(st); PH2_STORE(4)
    do_sweep<1, 2, 3>(st); PH2_STORE(5)
#undef PH2_STORE

    // ---- epilogue: remaining biases live on lane2 comp2, slots 0,1 ----
    const float b0 = bcast<2>(st[0][2]);
    const float b1 = bcast<2>(st[1][2]);
    LC += -0.5f * (LOG_2PI + b0 * b0);
    LC += -0.5f * (LOG_2PI + b1 * b1);
    if (q == 0) outL[p] = LC;
}

extern "C" void kernel_launch(void* const* d_in, const int* in_sizes, int n_in,
                              void* d_out, int out_size, void* d_ws, size_t ws_size,
                              hipStream_t stream) {
    const float* cur = (const float*)d_in[0];
    const float* nxt = (const float*)d_in[1];
    const float* bia = (const float*)d_in[2];
    float* out = (float*)d_out;

    // 4 threads per point: 256-thread blocks cover 64 points each.
    dim3 grid((NPc * 4) / 256), block(256);
    gaussmerge_kernel<<<grid, block, 0, stream>>>(cur, nxt, bia, out);
}